// Round 22
// baseline (182.299 us; speedup 1.0000x reference)
//
#include <hip/hip_runtime.h>

#define B_ 4
#define C_ 1024
#define T_ 2048
#define NH 16
#define DH 64
#define TC 3072   // 3*C: rows [0,2048)=W_mem (K then V), [2048,3072)=W_q

typedef __attribute__((ext_vector_type(8))) short short8;
typedef __attribute__((ext_vector_type(4))) short short4v;
typedef __attribute__((ext_vector_type(4))) float f32x4;
typedef __attribute__((ext_vector_type(16))) float f32x16;
typedef __attribute__((ext_vector_type(2))) unsigned int u32x2;
typedef __attribute__((ext_vector_type(4))) unsigned int u32x4;

#define S2Q 0.1803368801111204f   // 0.125 * log2(e), folded into Q at projection

static __device__ __forceinline__ unsigned short f2bf(float f){
  unsigned int u = __builtin_bit_cast(unsigned int, f);
  u += 0x7fffu + ((u >> 16) & 1u);
  return (unsigned short)(u >> 16);
}

// ---------------- cast W_mem||W_q -> bf16 Wc[3072][1024] ----------------
__global__ __launch_bounds__(256) void cast_w_kernel(const float* __restrict__ Wmem,
                                                     const float* __restrict__ Wq,
                                                     unsigned short* __restrict__ Wc){
  size_t base = ((size_t)blockIdx.x*256 + threadIdx.x)*4;
  float4 v;
  if (base < (size_t)2048*1024) v = *(const float4*)(Wmem + base);
  else                          v = *(const float4*)(Wq + (base - (size_t)2048*1024));
  short4v o;
  o.x = (short)f2bf(v.x); o.y = (short)f2bf(v.y);
  o.z = (short)f2bf(v.z); o.w = (short)f2bf(v.w);
  *(short4v*)(Wc + base) = o;
}

// ---------------- mask scan: compacted key index, nk128, pad bias ----------------
__global__ __launch_bounds__(256) void scan_mask_kernel(const int* __restrict__ mask,
    int* __restrict__ idx, int* __restrict__ nkinfo, float* __restrict__ cbias){
  __shared__ int cnt[256];
  int b = blockIdx.x;
  int tid = threadIdx.x;
  const int* mb = mask + (size_t)b*T_;
  int base = tid*8;
  int m[8]; int c = 0;
  #pragma unroll
  for (int i=0;i<8;i++){ m[i] = mb[base+i]; c += m[i]; }
  cnt[tid] = c;
  __syncthreads();
  for (int off=1; off<256; off<<=1){
    int v = (tid >= off) ? cnt[tid-off] : 0;
    __syncthreads();
    cnt[tid] += v;
    __syncthreads();
  }
  int nk  = cnt[255];
  int pos = cnt[tid] - c;
  #pragma unroll
  for (int i=0;i<8;i++){
    if (m[i]) idx[(size_t)b*T_ + (pos++)] = base + i;
  }
  #pragma unroll
  for (int i=0;i<8;i++){
    int j = base + i;
    cbias[(size_t)b*T_ + j] = (j < nk) ? 0.f : -1e30f;
  }
  if (tid == 0){
    nkinfo[b]   = (nk + 127) & ~127;  // nk128
    nkinfo[4+b] = nk;
  }
}

// ---------------- transpose-cast x[B][C][T] f32 -> xT[B][T][C] bf16 ----------------
__global__ __launch_bounds__(256) void transpose_x_kernel(const float* __restrict__ x,
                                                          unsigned short* __restrict__ xT){
  __shared__ float tile[32][33];
  int b = blockIdx.z;
  int c0 = blockIdx.y*32, t0 = blockIdx.x*32;
  int tx = threadIdx.x, ty = threadIdx.y;
  const float* xp = x + ((size_t)b*C_ + c0)*T_ + t0;
  #pragma unroll
  for (int i=0;i<4;i++) tile[ty+8*i][tx] = xp[(size_t)(ty+8*i)*T_ + tx];
  __syncthreads();
  unsigned short* op = xT + ((size_t)b*T_ + t0)*C_ + c0;
  int cp = tx & 15, tw = tx >> 4;
  #pragma unroll
  for (int i=0;i<2;i++){
    int trow = ty + 8*tw + 16*i;
    unsigned int pk = (unsigned int)f2bf(tile[2*cp][trow])
                    | ((unsigned int)f2bf(tile[2*cp+1][trow]) << 16);
    *(unsigned int*)(op + (size_t)trow*C_ + 2*cp) = pk;
  }
}

// ---------------- projection GEMM: 8-wave 256x128, balanced live-tile loop ----------------
// grid (128, B). Block d walks live tiles i = d, d+128, ... < L where
// L = 64 Q-tiles + 8*(nk128/128) KV-tiles. KV tiles gather B rows through idx[]
// (K/V emerge compacted in Kb/Vt; pad rows j>=nk clamp to row 0 -> finite garbage
// neutralized by cbias in attn). Q tiles use identity rows. No early-exit idles,
// no dead-tile FLOPs, no compact_kv pass.
#define PBM 256
#define PBN 128
#define PBK 64

__global__ __launch_bounds__(512) void proj_gemm_kernel(const unsigned short* __restrict__ Wc,
    const unsigned short* __restrict__ xT, const int* __restrict__ idx,
    const int* __restrict__ nkinfo,
    unsigned short* __restrict__ Kb, unsigned short* __restrict__ Vt,
    unsigned short* __restrict__ Qb){
  __shared__ unsigned short sA[PBM*PBK];   // 32KB
  __shared__ unsigned short sB[PBN*PBK];   // 16KB
  const int b = blockIdx.y;
  const int d = blockIdx.x;               // [0,128)
  const int nk128 = nkinfo[b], nk = nkinfo[4+b];
  const int L = 64 + 8*(nk128 >> 7);      // live tiles this batch
  const int tid = threadIdx.x;
  const int lane = tid & 63, wave = tid >> 6;
  const int wr = wave >> 1, wc = wave & 1;
  const unsigned short* xTb = xT + (size_t)b*T_*C_;
  auto ldsA = (__attribute__((address_space(3))) char*)sA;
  auto ldsB = (__attribute__((address_space(3))) char*)sB;
  const int l15 = lane & 15, lg4 = (lane >> 4)*16;

  for (int i = d; i < L; i += 128){
    int o0, t0;
    bool isKV;
    if (i < 64){ o0 = 2048 + (i >> 4)*PBM; t0 = (i & 15)*PBN; isKV = false; }
    else       { int k = i - 64; o0 = (k & 7)*PBM; t0 = (k >> 3)*PBN; isKV = true; }
    const unsigned short* Abase = Wc + (size_t)o0*C_;
    f32x4 acc[4][4] = {};
    // per-lane B-row source pointers (gathered for KV tiles)
    const char* srcBrow[2];
    #pragma unroll
    for (int i2=0;i2<2;i2++){
      int Ll = wave*2048 + i2*1024 + lane*16;
      int row = Ll >> 7, jb = Ll & 127;
      int t = t0 + row;
      int grow = isKV ? ((t < nk) ? idx[(size_t)b*T_ + t] : 0) : t;
      srcBrow[i2] = (const char*)(xTb + (size_t)grow*C_) + jb;
    }
    for (int k0=0; k0<C_; k0+=PBK){
      #pragma unroll
      for (int i2=0;i2<4;i2++){
        int Lb = wave*4096 + i2*1024;
        int Ll = Lb + lane*16;
        int row = Ll >> 7, jb = Ll & 127;
        const char* srcA = (const char*)(Abase + (size_t)row*C_ + k0) + jb;
        __builtin_amdgcn_global_load_lds((const __attribute__((address_space(1))) void*)srcA,
                                         (__attribute__((address_space(3))) void*)(ldsA + Lb), 16, 0, 0);
      }
      #pragma unroll
      for (int i2=0;i2<2;i2++){
        int Lb = wave*2048 + i2*1024;
        const char* srcB = srcBrow[i2] + (size_t)k0*2;
        __builtin_amdgcn_global_load_lds((const __attribute__((address_space(1))) void*)srcB,
                                         (__attribute__((address_space(3))) void*)(ldsB + Lb), 16, 0, 0);
      }
      __syncthreads();
      #pragma unroll
      for (int ks=0; ks<2; ks++){
        short8 af[4], bfr[4];
        #pragma unroll
        for (int m=0;m<4;m++){
          int row = wr*64 + m*16 + l15;
          af[m] = *(const short8*)((const char*)sA + row*128 + ks*64 + lg4);
        }
        #pragma unroll
        for (int n=0;n<4;n++){
          int row = wc*64 + n*16 + l15;
          bfr[n] = *(const short8*)((const char*)sB + row*128 + ks*64 + lg4);
        }
        #pragma unroll
        for (int m=0;m<4;m++){
          #pragma unroll
          for (int n=0;n<4;n++)
            acc[m][n] = __builtin_amdgcn_mfma_f32_16x16x32_bf16(af[m], bfr[n], acc[m][n], 0, 0, 0);
        }
      }
      __syncthreads();
    }
    int rowbase = o0 + wr*64;
    #pragma unroll
    for (int m=0;m<4;m++){
      int o = rowbase + m*16 + ((lane>>4)*4);
      #pragma unroll
      for (int n=0;n<4;n++){
        int t = t0 + wc*64 + n*16 + l15;
        f32x4 v = acc[m][n];
        if (o < C_){
          int h = o >> 6, dd = o & 63;
          unsigned short* p = Kb + (((size_t)(b*NH + h)*T_ + t)*DH + dd);
          short4v s; s.x=(short)f2bf(v.x); s.y=(short)f2bf(v.y);
          s.z=(short)f2bf(v.z); s.w=(short)f2bf(v.w);
          *(short4v*)p = s;
        } else if (o < 2*C_){
          int oo = o - C_;
          int h = oo >> 6, dd = oo & 63;
          unsigned short* p = Vt + (((size_t)(b*NH + h)*DH + dd)*T_ + t);
          p[0]    = f2bf(v.x);
          p[T_]   = f2bf(v.y);
          p[2*T_] = f2bf(v.z);
          p[3*T_] = f2bf(v.w);
        } else {
          int oo = o - 2*C_;
          int h = oo >> 6, dd = oo & 63;
          unsigned short* p = Qb + (((size_t)(b*NH + h)*T_ + t)*DH + dd);
          short4v s; s.x=(short)f2bf(v.x*S2Q); s.y=(short)f2bf(v.y*S2Q);
          s.z=(short)f2bf(v.z*S2Q); s.w=(short)f2bf(v.w*S2Q);
          *(short4v*)p = s;
        }
      }
    }
    __syncthreads();   // LDS free before next tile's staging
  }
}

// ---------------- flash attention over compacted keys (r14 structure, dynamic ntiles) ----------------
#define KB_ 64

#define GLL(SRC, SHBUF, LOFF) \
  __builtin_amdgcn_global_load_lds((const __attribute__((address_space(1))) void*)(SRC), \
      (__attribute__((address_space(3))) void*)((__attribute__((address_space(3))) char*)(SHBUF) + (LOFF)), 16, 0, 0)

#define MAX3(a,b,c) fmaxf(fmaxf((a),(b)),(c))

__global__ __launch_bounds__(256) void attn_kernel(const unsigned short* __restrict__ Qb,
    const unsigned short* __restrict__ Kb, const unsigned short* __restrict__ Vt,
    const float* __restrict__ cbias, const int* __restrict__ nkinfo,
    float* __restrict__ out){
  __shared__ unsigned short sK[2][KB_*DH];
  __shared__ unsigned short sV[2][KB_*DH];
  const int Lid = blockIdx.x;
  const int xcd = Lid & 7, jj = Lid >> 3;
  const int bh = ((jj & 7) << 3) | xcd;
  const int qblk = jj >> 3;
  const int b = bh >> 4;
  const int ntiles = nkinfo[b] >> 6;
  const int tid = threadIdx.x, lane = tid & 63, wave = tid >> 6;
  const int l31 = lane & 31, h = lane >> 5;
  const int rsw = l31 & 7;
  const unsigned short* Kbase = Kb + (size_t)bh*T_*DH;
  const unsigned short* Vbase = Vt + (size_t)bh*DH*T_;
  const float* bptr = cbias + (size_t)b*T_ + 4*h;
  const int qrow = qblk*128 + wave*32 + l31;
  const unsigned short* Qp = Qb + ((size_t)bh*T_ + qrow)*DH + h*8;
  short8 qf[4];
  #pragma unroll
  for (int kc=0;kc<4;kc++) qf[kc] = *(const short8*)(Qp + kc*16);
  f32x16 acco0 = {}, acco1 = {};
  float mrun = -1e30f, lpart = 0.f;
  const int L0  = wave*2048;
  const int Ll0 = L0 + lane*16, Ll1 = Ll0 + 1024;
  const int row0 = Ll0 >> 7, row1 = Ll1 >> 7;
  const int cg0 = ((Ll0 >> 4) & 7) ^ (row0 & 7);
  const int cg1 = ((Ll1 >> 4) & 7) ^ (row1 & 7);
  const char* srcK0 = (const char*)Kbase + row0*128 + cg0*16;
  const char* srcK1 = (const char*)Kbase + row1*128 + cg1*16;
  const char* srcV0 = (const char*)Vbase + (size_t)row0*(T_*2) + cg0*16;
  const char* srcV1 = (const char*)Vbase + (size_t)row1*(T_*2) + cg1*16;

  GLL(srcK0, &sK[0][0], L0);
  GLL(srcK1, &sK[0][0], L0 + 1024);
  GLL(srcV0, &sV[0][0], L0);
  GLL(srcV1, &sV[0][0], L0 + 1024);
  srcK0 += 8192; srcK1 += 8192; srcV0 += 128; srcV1 += 128;
  __syncthreads();

  for (int kt = 0; kt < ntiles; kt++){
    const int cb = kt & 1;
    union { f32x4 q[4]; f32x16 v; } cb0, cb1;
    #pragma unroll
    for (int m=0;m<4;m++){
      cb0.q[m] = *(const f32x4*)(bptr + m*8);
      cb1.q[m] = *(const f32x4*)(bptr + 32 + m*8);
    }
    bptr += 64;
    if (kt + 1 < ntiles){
      int db = cb ^ 1;
      GLL(srcK0, &sK[0][0], db*8192 + L0);
      GLL(srcK1, &sK[0][0], db*8192 + L0 + 1024);
      GLL(srcV0, &sV[0][0], db*8192 + L0);
      GLL(srcV1, &sV[0][0], db*8192 + L0 + 1024);
      srcK0 += 8192; srcK1 += 8192; srcV0 += 128; srcV1 += 128;
      asm volatile("s_waitcnt vmcnt(12)" ::: "memory");
    } else {
      asm volatile("s_waitcnt vmcnt(8)" ::: "memory");
    }
    __builtin_amdgcn_s_barrier();
    __builtin_amdgcn_sched_barrier(0);
    const char* sKb = (const char*)&sK[0][0] + cb*8192 + l31*128;
    const char* sVb = (const char*)&sV[0][0] + cb*8192 + l31*128;
    f32x16 s0 = cb0.v, s1 = cb1.v;
    #pragma unroll
    for (int kc=0;kc<4;kc++){
      int co = (((kc<<1)|h) ^ rsw) << 4;
      short8 kf0 = *(const short8*)(sKb + co);
      short8 kf1 = *(const short8*)(sKb + 4096 + co);
      s0 = __builtin_amdgcn_mfma_f32_32x32x16_bf16(kf0, qf[kc], s0, 0,0,0);
      s1 = __builtin_amdgcn_mfma_f32_32x32x16_bf16(kf1, qf[kc], s1, 0,0,0);
    }
    float t0_ = MAX3(s0[0],s0[1],s0[2]),   t1_ = MAX3(s0[3],s0[4],s0[5]);
    float t2_ = MAX3(s0[6],s0[7],s0[8]),   t3_ = MAX3(s0[9],s0[10],s0[11]);
    float t4_ = MAX3(s0[12],s0[13],s0[14]), t5_ = MAX3(s0[15],s1[0],s1[1]);
    float t6_ = MAX3(s1[2],s1[3],s1[4]),   t7_ = MAX3(s1[5],s1[6],s1[7]);
    float t8_ = MAX3(s1[8],s1[9],s1[10]),  t9_ = MAX3(s1[11],s1[12],s1[13]);
    float u0_ = MAX3(t0_,t1_,t2_), u1_ = MAX3(t3_,t4_,t5_);
    float u2_ = MAX3(t6_,t7_,t8_), u3_ = MAX3(t9_,s1[14],s1[15]);
    float pmax = MAX3(MAX3(u0_,u1_,u2_), u3_, -1e30f);
    if (!__all(pmax - mrun <= 8.0f)){
      float pm = fmaxf(pmax, __shfl_xor(pmax, 32));
      float mnew = fmaxf(mrun, pm);
      float alpha = __builtin_amdgcn_exp2f(mrun - mnew);
      mrun = mnew; lpart *= alpha;
      #pragma unroll
      for (int r=0;r<16;r++){
        float ar = __shfl(alpha, (r&3) + 8*(r>>2) + 4*h);
        acco0[r] *= ar; acco1[r] *= ar;
      }
    }
    float ps_ = 0.f;
    #pragma unroll
    for (int j=0;j<16;j++){
      s0[j] = __builtin_amdgcn_exp2f(s0[j] - mrun); ps_ += s0[j];
      s1[j] = __builtin_amdgcn_exp2f(s1[j] - mrun); ps_ += s1[j];
    }
    lpart += ps_;
    unsigned int Wp[2][4][2];
    #pragma unroll
    for (int m=0;m<4;m++){
      asm volatile("v_cvt_pk_bf16_f32 %0, %1, %2" : "=v"(Wp[0][m][0]) : "v"(s0[4*m]),   "v"(s0[4*m+1]));
      asm volatile("v_cvt_pk_bf16_f32 %0, %1, %2" : "=v"(Wp[0][m][1]) : "v"(s0[4*m+2]), "v"(s0[4*m+3]));
      asm volatile("v_cvt_pk_bf16_f32 %0, %1, %2" : "=v"(Wp[1][m][0]) : "v"(s1[4*m]),   "v"(s1[4*m+1]));
      asm volatile("v_cvt_pk_bf16_f32 %0, %1, %2" : "=v"(Wp[1][m][1]) : "v"(s1[4*m+2]), "v"(s1[4*m+3]));
    }
    #pragma unroll
    for (int kb=0;kb<2;kb++){
      #pragma unroll
      for (int e=0;e<2;e++){
        u32x2 x0 = __builtin_amdgcn_permlane32_swap(Wp[kb][2*e][0], Wp[kb][2*e+1][0], 0, 0);
        u32x2 x1 = __builtin_amdgcn_permlane32_swap(Wp[kb][2*e][1], Wp[kb][2*e+1][1], 0, 0);
        u32x4 pw; pw.x = x0.x; pw.y = x1.x; pw.z = x0.y; pw.w = x1.y;
        short8 pf = __builtin_bit_cast(short8, pw);
        int vo = (((((kb<<1)|e)<<1)|h) ^ rsw) << 4;
        short8 vf0 = *(const short8*)(sVb + vo);
        short8 vf1 = *(const short8*)(sVb + 4096 + vo);
        acco0 = __builtin_amdgcn_mfma_f32_32x32x16_bf16(pf, vf0, acco0, 0,0,0);
        acco1 = __builtin_amdgcn_mfma_f32_32x32x16_bf16(pf, vf1, acco1, 0,0,0);
      }
    }
    __builtin_amdgcn_sched_barrier(0);
    __builtin_amdgcn_s_barrier();
  }

  lpart += __shfl_xor(lpart, 32);
  float inv = 1.0f / lpart;
  const int head = bh & 15;
  const int qbase = qblk*128 + wave*32;
  #pragma unroll
  for (int m=0;m<4;m++){
    float rv[4];
    #pragma unroll
    for (int s=0;s<4;s++) rv[s] = __shfl(inv, 8*m + 4*h + s);
    int t = qbase + 8*m + 4*h;
    float4 v0, v1;
    v0.x = acco0[4*m+0]*rv[0]; v0.y = acco0[4*m+1]*rv[1];
    v0.z = acco0[4*m+2]*rv[2]; v0.w = acco0[4*m+3]*rv[3];
    v1.x = acco1[4*m+0]*rv[0]; v1.y = acco1[4*m+1]*rv[1];
    v1.z = acco1[4*m+2]*rv[2]; v1.w = acco1[4*m+3]*rv[3];
    size_t off0 = ((size_t)b*C_ + head*64 + l31)*T_ + t;
    size_t off1 = ((size_t)b*C_ + head*64 + 32 + l31)*T_ + t;
    *(float4*)(out + off0) = v0;
    *(float4*)(out + off1) = v1;
  }
}

extern "C" void kernel_launch(void* const* d_in, const int* in_sizes, int n_in,
                              void* d_out, int out_size, void* d_ws, size_t ws_size,
                              hipStream_t stream) {
  const float* x    = (const float*)d_in[0];
  const int*   mask = (const int*)d_in[1];
  const float* Wmem = (const float*)d_in[2];
  const float* Wq   = (const float*)d_in[3];
  float* out = (float*)d_out;

  unsigned short* ws = (unsigned short*)d_ws;
  unsigned short* xT = ws;                                   // B*T*C
  unsigned short* Wc = xT + (size_t)B_*T_*C_;                // TC*C
  unsigned short* Qb = Wc + (size_t)TC*C_;                   // B*NH*T*DH
  unsigned short* Kb = Qb + (size_t)B_*NH*T_*DH;
  unsigned short* Vt = Kb + (size_t)B_*NH*T_*DH;
  float* cbias = (float*)(Vt + (size_t)B_*NH*T_*DH);         // B*T floats
  int*   idx   = (int*)(cbias + (size_t)B_*T_);              // B*T ints
  int*   nkinfo = idx + (size_t)B_*T_;                       // 8 ints

  cast_w_kernel<<<dim3(TC*C_/1024), dim3(256), 0, stream>>>(Wmem, Wq, Wc);
  scan_mask_kernel<<<dim3(B_), dim3(256), 0, stream>>>(mask, idx, nkinfo, cbias);
  transpose_x_kernel<<<dim3(T_/32, C_/32, B_), dim3(32,8), 0, stream>>>(x, xT);
  proj_gemm_kernel<<<dim3(128, B_), dim3(512), 0, stream>>>(Wc, xT, idx, nkinfo, Kb, Vt, Qb);
  attn_kernel<<<dim3((T_/128)*(B_*NH)), dim3(256), 0, stream>>>(Qb, Kb, Vt, cbias, nkinfo, out);
}

// Round 23
// 165.425 us; speedup vs baseline: 1.1020x; 1.1020x over previous
//
#include <hip/hip_runtime.h>

#define B_ 4
#define C_ 1024
#define T_ 2048
#define NH 16
#define DH 64
#define TC 3072   // 3*C: rows [0,2048)=W_mem (K then V), [2048,3072)=W_q

typedef __attribute__((ext_vector_type(8))) short short8;
typedef __attribute__((ext_vector_type(4))) short short4v;
typedef __attribute__((ext_vector_type(4))) float f32x4;
typedef __attribute__((ext_vector_type(16))) float f32x16;
typedef __attribute__((ext_vector_type(2))) unsigned int u32x2;
typedef __attribute__((ext_vector_type(4))) unsigned int u32x4;

#define S2Q 0.1803368801111204f   // 0.125 * log2(e), folded into Q at projection

static __device__ __forceinline__ unsigned short f2bf(float f){
  unsigned int u = __builtin_bit_cast(unsigned int, f);
  u += 0x7fffu + ((u >> 16) & 1u);
  return (unsigned short)(u >> 16);
}

// ---------------- cast W_mem||W_q -> bf16 Wc[3072][1024] ----------------
__global__ __launch_bounds__(256) void cast_w_kernel(const float* __restrict__ Wmem,
                                                     const float* __restrict__ Wq,
                                                     unsigned short* __restrict__ Wc){
  size_t base = ((size_t)blockIdx.x*256 + threadIdx.x)*4;
  float4 v;
  if (base < (size_t)2048*1024) v = *(const float4*)(Wmem + base);
  else                          v = *(const float4*)(Wq + (base - (size_t)2048*1024));
  short4v o;
  o.x = (short)f2bf(v.x); o.y = (short)f2bf(v.y);
  o.z = (short)f2bf(v.z); o.w = (short)f2bf(v.w);
  *(short4v*)(Wc + base) = o;
}

// ---------------- mask scan: compacted key index, nk128, pad bias ----------------
__global__ __launch_bounds__(256) void scan_mask_kernel(const int* __restrict__ mask,
    int* __restrict__ idx, int* __restrict__ nkinfo, float* __restrict__ cbias){
  __shared__ int cnt[256];
  int b = blockIdx.x;
  int tid = threadIdx.x;
  const int* mb = mask + (size_t)b*T_;
  int base = tid*8;
  int m[8]; int c = 0;
  #pragma unroll
  for (int i=0;i<8;i++){ m[i] = mb[base+i]; c += m[i]; }
  cnt[tid] = c;
  __syncthreads();
  for (int off=1; off<256; off<<=1){
    int v = (tid >= off) ? cnt[tid-off] : 0;
    __syncthreads();
    cnt[tid] += v;
    __syncthreads();
  }
  int nk  = cnt[255];
  int pos = cnt[tid] - c;
  #pragma unroll
  for (int i=0;i<8;i++){
    if (m[i]) idx[(size_t)b*T_ + (pos++)] = base + i;
  }
  #pragma unroll
  for (int i=0;i<8;i++){
    int j = base + i;
    cbias[(size_t)b*T_ + j] = (j < nk) ? 0.f : -1e30f;
  }
  if (tid == 0){
    nkinfo[b]   = (nk + 127) & ~127;  // nk128
    nkinfo[4+b] = nk;
  }
}

// ---------------- transpose-cast x[B][C][T] f32 -> xT[B][T][C] bf16 ----------------
__global__ __launch_bounds__(256) void transpose_x_kernel(const float* __restrict__ x,
                                                          unsigned short* __restrict__ xT){
  __shared__ float tile[32][33];
  int b = blockIdx.z;
  int c0 = blockIdx.y*32, t0 = blockIdx.x*32;
  int tx = threadIdx.x, ty = threadIdx.y;
  const float* xp = x + ((size_t)b*C_ + c0)*T_ + t0;
  #pragma unroll
  for (int i=0;i<4;i++) tile[ty+8*i][tx] = xp[(size_t)(ty+8*i)*T_ + tx];
  __syncthreads();
  unsigned short* op = xT + ((size_t)b*T_ + t0)*C_ + c0;
  int cp = tx & 15, tw = tx >> 4;
  #pragma unroll
  for (int i=0;i<2;i++){
    int trow = ty + 8*tw + 16*i;
    unsigned int pk = (unsigned int)f2bf(tile[2*cp][trow])
                    | ((unsigned int)f2bf(tile[2*cp+1][trow]) << 16);
    *(unsigned int*)(op + (size_t)trow*C_ + 2*cp) = pk;
  }
}

// ---------------- projection GEMM (m97 structure; Q pre-scaled by S2Q) ----------------
// r15 structure (inline idx-gather for KV rows, dead-tile early exit) +
// XCD-aware 2D chunk swizzle — xcd=d&7 selects (o-quarter, t-parity) so each
// XCD's working set fits its 4MB L2; t-parity interleave balances dead KV tiles.
#define PBM 128
#define PBN 128
#define PBK 64

__global__ __launch_bounds__(256) void proj_gemm_kernel(const unsigned short* __restrict__ Wc,
    const unsigned short* __restrict__ xT, const int* __restrict__ idx,
    const int* __restrict__ nkinfo,
    unsigned short* __restrict__ Kb, unsigned short* __restrict__ Vt,
    unsigned short* __restrict__ Qb){
  __shared__ unsigned short sA[PBM*PBK];
  __shared__ unsigned short sB[PBN*PBK];
  int b = blockIdx.y;
  int d = blockIdx.x;
  int xcd = d & 7, j = d >> 3;
  int oq = xcd >> 1, th = xcd & 1;
  int o0 = (oq*6 + (j % 6)) * PBM;
  int t0 = ((j/6)*2 + th) * PBN;
  const bool isKV = (o0 < 2*C_);
  const int nk128 = nkinfo[b], nk = nkinfo[4+b];
  if (isKV && t0 >= nk128) return;
  int tid = threadIdx.x;
  int lane = tid & 63, wave = tid >> 6;
  int wr = wave >> 1, wc = wave & 1;
  f32x4 acc[4][4] = {};
  const unsigned short* Abase = Wc + (size_t)o0*C_;
  const unsigned short* xTb = xT + (size_t)b*T_*C_;
  auto ldsA = (__attribute__((address_space(3))) char*)sA;
  auto ldsB = (__attribute__((address_space(3))) char*)sB;
  const char* srcBrow[4];
  #pragma unroll
  for (int i=0;i<4;i++){
    int L  = wave*4096 + i*1024;
    int Ll = L + lane*16;
    int row = Ll >> 7;
    int jb  = Ll & 127;
    int trow = t0 + row;
    int grow = trow;
    if (isKV) grow = (trow < nk) ? idx[(size_t)b*T_ + trow] : 0;
    srcBrow[i] = (const char*)(xTb + (size_t)grow*C_) + jb;
  }
  for (int k0=0; k0<C_; k0+=PBK){
    #pragma unroll
    for (int i=0;i<4;i++){
      int L  = wave*4096 + i*1024;
      int Ll = L + lane*16;
      int row = Ll >> 7;
      int jb  = Ll & 127;
      const char* srcA = (const char*)(Abase + (size_t)row*C_ + k0) + jb;
      const char* srcB = srcBrow[i] + (size_t)k0*2;
      __builtin_amdgcn_global_load_lds((const __attribute__((address_space(1))) void*)srcA,
                                       (__attribute__((address_space(3))) void*)(ldsA + L), 16, 0, 0);
      __builtin_amdgcn_global_load_lds((const __attribute__((address_space(1))) void*)srcB,
                                       (__attribute__((address_space(3))) void*)(ldsB + L), 16, 0, 0);
    }
    __syncthreads();
    #pragma unroll
    for (int ks=0; ks<2; ks++){
      short8 af[4], bfr[4];
      #pragma unroll
      for (int m=0;m<4;m++){
        int row = wr*64 + m*16 + (lane & 15);
        af[m] = *(const short8*)((const char*)sA + row*128 + ks*64 + ((lane>>4)*16));
      }
      #pragma unroll
      for (int n=0;n<4;n++){
        int row = wc*64 + n*16 + (lane & 15);
        bfr[n] = *(const short8*)((const char*)sB + row*128 + ks*64 + ((lane>>4)*16));
      }
      #pragma unroll
      for (int m=0;m<4;m++){
        #pragma unroll
        for (int n=0;n<4;n++)
          acc[m][n] = __builtin_amdgcn_mfma_f32_16x16x32_bf16(af[m], bfr[n], acc[m][n], 0, 0, 0);
      }
    }
    __syncthreads();
  }
  int rowbase = o0 + wr*64;
  #pragma unroll
  for (int m=0;m<4;m++){
    int o = rowbase + m*16 + ((lane>>4)*4);
    #pragma unroll
    for (int n=0;n<4;n++){
      int t = t0 + wc*64 + n*16 + (lane & 15);
      f32x4 v = acc[m][n];
      if (o < C_){
        int h = o >> 6, dd = o & 63;
        unsigned short* p = Kb + (((size_t)(b*NH + h)*T_ + t)*DH + dd);
        short4v s; s.x=(short)f2bf(v.x); s.y=(short)f2bf(v.y);
        s.z=(short)f2bf(v.z); s.w=(short)f2bf(v.w);
        *(short4v*)p = s;
      } else if (o < 2*C_){
        int oo = o - C_;
        int h = oo >> 6, dd = oo & 63;
        unsigned short* p = Vt + (((size_t)(b*NH + h)*DH + dd)*T_ + t);
        p[0]    = f2bf(v.x);
        p[T_]   = f2bf(v.y);
        p[2*T_] = f2bf(v.z);
        p[3*T_] = f2bf(v.w);
      } else {
        int oo = o - 2*C_;
        int h = oo >> 6, dd = oo & 63;
        unsigned short* p = Qb + (((size_t)(b*NH + h)*T_ + t)*DH + dd);
        short4v s; s.x=(short)f2bf(v.x*S2Q); s.y=(short)f2bf(v.y*S2Q);
        s.z=(short)f2bf(v.z*S2Q); s.w=(short)f2bf(v.w*S2Q);
        *(short4v*)p = s;
      }
    }
  }
}

// ---------------- flash attention over compacted keys (r14 structure, dynamic ntiles) ----------------
#define KB_ 64

#define GLL(SRC, SHBUF, LOFF) \
  __builtin_amdgcn_global_load_lds((const __attribute__((address_space(1))) void*)(SRC), \
      (__attribute__((address_space(3))) void*)((__attribute__((address_space(3))) char*)(SHBUF) + (LOFF)), 16, 0, 0)

#define MAX3(a,b,c) fmaxf(fmaxf((a),(b)),(c))

__global__ __launch_bounds__(256) void attn_kernel(const unsigned short* __restrict__ Qb,
    const unsigned short* __restrict__ Kb, const unsigned short* __restrict__ Vt,
    const float* __restrict__ cbias, const int* __restrict__ nkinfo,
    float* __restrict__ out){
  __shared__ unsigned short sK[2][KB_*DH];   // [key][d] swizzled, dbuf (8KB each)
  __shared__ unsigned short sV[2][KB_*DH];   // [d][key] swizzled, dbuf
  // XCD-local remap (1024 blocks): all 16 qblk of one bh share L%8.
  const int Lid = blockIdx.x;
  const int xcd = Lid & 7, jj = Lid >> 3;
  const int bh = ((jj & 7) << 3) | xcd;
  const int qblk = jj >> 3;
  const int b = bh >> 4;
  const int ntiles = nkinfo[b] >> 6;   // nk128/64, >= 2
  const int tid = threadIdx.x, lane = tid & 63, wave = tid >> 6;
  const int l31 = lane & 31, h = lane >> 5;
  const int rsw = l31 & 7;
  const unsigned short* Kbase = Kb + (size_t)bh*T_*DH;
  const unsigned short* Vbase = Vt + (size_t)bh*DH*T_;
  const float* bptr = cbias + (size_t)b*T_ + 4*h;
  const int qrow = qblk*128 + wave*32 + l31;
  const unsigned short* Qp = Qb + ((size_t)bh*T_ + qrow)*DH + h*8;
  short8 qf[4];
  #pragma unroll
  for (int kc=0;kc<4;kc++) qf[kc] = *(const short8*)(Qp + kc*16);
  f32x16 acco0 = {}, acco1 = {};
  float mrun = -1e30f, lpart = 0.f;
  const int L0  = wave*2048;
  const int Ll0 = L0 + lane*16, Ll1 = Ll0 + 1024;
  const int row0 = Ll0 >> 7, row1 = Ll1 >> 7;
  const int cg0 = ((Ll0 >> 4) & 7) ^ (row0 & 7);
  const int cg1 = ((Ll1 >> 4) & 7) ^ (row1 & 7);
  const char* srcK0 = (const char*)Kbase + row0*128 + cg0*16;
  const char* srcK1 = (const char*)Kbase + row1*128 + cg1*16;
  const char* srcV0 = (const char*)Vbase + (size_t)row0*(T_*2) + cg0*16;
  const char* srcV1 = (const char*)Vbase + (size_t)row1*(T_*2) + cg1*16;

  GLL(srcK0, &sK[0][0], L0);
  GLL(srcK1, &sK[0][0], L0 + 1024);
  GLL(srcV0, &sV[0][0], L0);
  GLL(srcV1, &sV[0][0], L0 + 1024);
  srcK0 += 8192; srcK1 += 8192; srcV0 += 128; srcV1 += 128;
  __syncthreads();

  for (int kt = 0; kt < ntiles; kt++){
    const int cb = kt & 1;
    union { f32x4 q[4]; f32x16 v; } cb0, cb1;
    #pragma unroll
    for (int m=0;m<4;m++){
      cb0.q[m] = *(const f32x4*)(bptr + m*8);
      cb1.q[m] = *(const f32x4*)(bptr + 32 + m*8);
    }
    bptr += 64;
    if (kt + 1 < ntiles){
      int db = cb ^ 1;
      GLL(srcK0, &sK[0][0], db*8192 + L0);
      GLL(srcK1, &sK[0][0], db*8192 + L0 + 1024);
      GLL(srcV0, &sV[0][0], db*8192 + L0);
      GLL(srcV1, &sV[0][0], db*8192 + L0 + 1024);
      srcK0 += 8192; srcK1 += 8192; srcV0 += 128; srcV1 += 128;
      asm volatile("s_waitcnt vmcnt(12)" ::: "memory");
    } else {
      asm volatile("s_waitcnt vmcnt(8)" ::: "memory");
    }
    __builtin_amdgcn_s_barrier();
    __builtin_amdgcn_sched_barrier(0);
    const char* sKb = (const char*)&sK[0][0] + cb*8192 + l31*128;
    const char* sVb = (const char*)&sV[0][0] + cb*8192 + l31*128;
    f32x16 s0 = cb0.v, s1 = cb1.v;
    #pragma unroll
    for (int kc=0;kc<4;kc++){
      int co = (((kc<<1)|h) ^ rsw) << 4;
      short8 kf0 = *(const short8*)(sKb + co);
      short8 kf1 = *(const short8*)(sKb + 4096 + co);
      s0 = __builtin_amdgcn_mfma_f32_32x32x16_bf16(kf0, qf[kc], s0, 0,0,0);
      s1 = __builtin_amdgcn_mfma_f32_32x32x16_bf16(kf1, qf[kc], s1, 0,0,0);
    }
    float t0_ = MAX3(s0[0],s0[1],s0[2]),   t1_ = MAX3(s0[3],s0[4],s0[5]);
    float t2_ = MAX3(s0[6],s0[7],s0[8]),   t3_ = MAX3(s0[9],s0[10],s0[11]);
    float t4_ = MAX3(s0[12],s0[13],s0[14]), t5_ = MAX3(s0[15],s1[0],s1[1]);
    float t6_ = MAX3(s1[2],s1[3],s1[4]),   t7_ = MAX3(s1[5],s1[6],s1[7]);
    float t8_ = MAX3(s1[8],s1[9],s1[10]),  t9_ = MAX3(s1[11],s1[12],s1[13]);
    float u0_ = MAX3(t0_,t1_,t2_), u1_ = MAX3(t3_,t4_,t5_);
    float u2_ = MAX3(t6_,t7_,t8_), u3_ = MAX3(t9_,s1[14],s1[15]);
    float pmax = MAX3(MAX3(u0_,u1_,u2_), u3_, -1e30f);
    if (!__all(pmax - mrun <= 8.0f)){
      float pm = fmaxf(pmax, __shfl_xor(pmax, 32));
      float mnew = fmaxf(mrun, pm);
      float alpha = __builtin_amdgcn_exp2f(mrun - mnew);
      mrun = mnew; lpart *= alpha;
      #pragma unroll
      for (int r=0;r<16;r++){
        float ar = __shfl(alpha, (r&3) + 8*(r>>2) + 4*h);
        acco0[r] *= ar; acco1[r] *= ar;
      }
    }
    float ps_ = 0.f;
    #pragma unroll
    for (int j=0;j<16;j++){
      s0[j] = __builtin_amdgcn_exp2f(s0[j] - mrun); ps_ += s0[j];
      s1[j] = __builtin_amdgcn_exp2f(s1[j] - mrun); ps_ += s1[j];
    }
    lpart += ps_;
    unsigned int Wp[2][4][2];
    #pragma unroll
    for (int m=0;m<4;m++){
      asm volatile("v_cvt_pk_bf16_f32 %0, %1, %2" : "=v"(Wp[0][m][0]) : "v"(s0[4*m]),   "v"(s0[4*m+1]));
      asm volatile("v_cvt_pk_bf16_f32 %0, %1, %2" : "=v"(Wp[0][m][1]) : "v"(s0[4*m+2]), "v"(s0[4*m+3]));
      asm volatile("v_cvt_pk_bf16_f32 %0, %1, %2" : "=v"(Wp[1][m][0]) : "v"(s1[4*m]),   "v"(s1[4*m+1]));
      asm volatile("v_cvt_pk_bf16_f32 %0, %1, %2" : "=v"(Wp[1][m][1]) : "v"(s1[4*m+2]), "v"(s1[4*m+3]));
    }
    #pragma unroll
    for (int kb=0;kb<2;kb++){
      #pragma unroll
      for (int e=0;e<2;e++){
        u32x2 x0 = __builtin_amdgcn_permlane32_swap(Wp[kb][2*e][0], Wp[kb][2*e+1][0], 0, 0);
        u32x2 x1 = __builtin_amdgcn_permlane32_swap(Wp[kb][2*e][1], Wp[kb][2*e+1][1], 0, 0);
        u32x4 pw; pw.x = x0.x; pw.y = x1.x; pw.z = x0.y; pw.w = x1.y;
        short8 pf = __builtin_bit_cast(short8, pw);
        int vo = (((((kb<<1)|e)<<1)|h) ^ rsw) << 4;
        short8 vf0 = *(const short8*)(sVb + vo);
        short8 vf1 = *(const short8*)(sVb + 4096 + vo);
        acco0 = __builtin_amdgcn_mfma_f32_32x32x16_bf16(pf, vf0, acco0, 0,0,0);
        acco1 = __builtin_amdgcn_mfma_f32_32x32x16_bf16(pf, vf1, acco1, 0,0,0);
      }
    }
    __builtin_amdgcn_sched_barrier(0);
    __builtin_amdgcn_s_barrier();
  }

  lpart += __shfl_xor(lpart, 32);
  float inv = 1.0f / lpart;
  const int head = bh & 15;
  const int qbase = qblk*128 + wave*32;
  #pragma unroll
  for (int m=0;m<4;m++){
    float rv[4];
    #pragma unroll
    for (int s=0;s<4;s++) rv[s] = __shfl(inv, 8*m + 4*h + s);
    int t = qbase + 8*m + 4*h;
    float4 v0, v1;
    v0.x = acco0[4*m+0]*rv[0]; v0.y = acco0[4*m+1]*rv[1];
    v0.z = acco0[4*m+2]*rv[2]; v0.w = acco0[4*m+3]*rv[3];
    v1.x = acco1[4*m+0]*rv[0]; v1.y = acco1[4*m+1]*rv[1];
    v1.z = acco1[4*m+2]*rv[2]; v1.w = acco1[4*m+3]*rv[3];
    size_t off0 = ((size_t)b*C_ + head*64 + l31)*T_ + t;
    size_t off1 = ((size_t)b*C_ + head*64 + 32 + l31)*T_ + t;
    *(float4*)(out + off0) = v0;
    *(float4*)(out + off1) = v1;
  }
}

extern "C" void kernel_launch(void* const* d_in, const int* in_sizes, int n_in,
                              void* d_out, int out_size, void* d_ws, size_t ws_size,
                              hipStream_t stream) {
  const float* x    = (const float*)d_in[0];
  const int*   mask = (const int*)d_in[1];
  const float* Wmem = (const float*)d_in[2];
  const float* Wq   = (const float*)d_in[3];
  float* out = (float*)d_out;

  unsigned short* ws = (unsigned short*)d_ws;
  unsigned short* xT = ws;                                   // B*T*C
  unsigned short* Wc = xT + (size_t)B_*T_*C_;                // TC*C
  unsigned short* Qb = Wc + (size_t)TC*C_;                   // B*NH*T*DH
  unsigned short* Kb = Qb + (size_t)B_*NH*T_*DH;
  unsigned short* Vt = Kb + (size_t)B_*NH*T_*DH;
  float* cbias = (float*)(Vt + (size_t)B_*NH*T_*DH);         // B*T floats
  int*   idx   = (int*)(cbias + (size_t)B_*T_);              // B*T ints
  int*   nkinfo = idx + (size_t)B_*T_;                       // 8 ints

  cast_w_kernel<<<dim3(TC*C_/1024), dim3(256), 0, stream>>>(Wmem, Wq, Wc);
  scan_mask_kernel<<<dim3(B_), dim3(256), 0, stream>>>(mask, idx, nkinfo, cbias);
  transpose_x_kernel<<<dim3(T_/32, C_/32, B_), dim3(32,8), 0, stream>>>(x, xT);
  proj_gemm_kernel<<<dim3((TC/PBM)*(T_/PBN), B_), dim3(256), 0, stream>>>(Wc, xT, idx, nkinfo, Kb, Vt, Qb);
  attn_kernel<<<dim3((T_/128)*(B_*NH)), dim3(256), 0, stream>>>(Qb, Kb, Vt, cbias, nkinfo, out);
}